// Round 4
// baseline (390.865 us; speedup 1.0000x reference)
//
#include <hip/hip_runtime.h>
#include <hip/hip_bf16.h>
#include <stdint.h>

// MHA: B=4, T=2048, D=1024, H=16, Dh=64.  All MFMA in bf16 (16x16x32), fp32 accum.
// Pipeline: prep_w (W->W^T bf16) ; proj_gemm (Q,K,V^T bf16 bufs) ; attn (flash, causal) ;
// out_gemm (-> fp32 d_out).  Workspace: 72 MB.

typedef __attribute__((ext_vector_type(8))) short short8;   // 8 x bf16 = 4 VGPR (MFMA A/B frag)
typedef __attribute__((ext_vector_type(4))) float f32x4;    // MFMA C/D frag

__device__ __forceinline__ unsigned short f2bf(float f) {
  union { float f; unsigned u; } v; v.f = f;
  unsigned r = (v.u + 0x7fffu + ((v.u >> 16) & 1u)) >> 16;
  return (unsigned short)r;
}

__device__ __forceinline__ void gl_lds16(const void* g, void* l) {
  __builtin_amdgcn_global_load_lds((const __attribute__((address_space(1))) void*)g,
                                   (__attribute__((address_space(3))) void*)l, 16, 0, 0);
}

// ---------------------------------------------------------------------------
// Kernel 1: transpose+convert weights. W[k][n] fp32 -> WT[n][k] bf16.
// z: 0..3 = Wq,Wk,Wv,Wo. grid (16,16,4), block 256.
__global__ __launch_bounds__(256) void prep_w(const float* __restrict__ Wq,
                                              const float* __restrict__ Wk,
                                              const float* __restrict__ Wv,
                                              const float* __restrict__ Wo,
                                              unsigned short* __restrict__ WT) {
  int z = blockIdx.z;
  const float* W = (z == 0) ? Wq : (z == 1) ? Wk : (z == 2) ? Wv : Wo;
  unsigned short* dst = WT + (size_t)z * 1024 * 1024;
  int k0 = blockIdx.x * 64, n0 = blockIdx.y * 64;
  __shared__ float tile[64][65];
  int tid = threadIdx.x;
#pragma unroll
  for (int j = 0; j < 4; ++j) {
    int u = tid + j * 256;            // 1024 units of float4
    int row = u >> 4, c4 = u & 15;
    float4 v = *(const float4*)(W + (size_t)(k0 + row) * 1024 + n0 + c4 * 4);
    tile[row][c4 * 4 + 0] = v.x;
    tile[row][c4 * 4 + 1] = v.y;
    tile[row][c4 * 4 + 2] = v.z;
    tile[row][c4 * 4 + 3] = v.w;
  }
  __syncthreads();
#pragma unroll
  for (int j = 0; j < 2; ++j) {
    int u = tid + j * 256;            // 512 units of 8 bf16
    int nrow = u >> 3, kc = u & 7;
    unsigned e[8];
#pragma unroll
    for (int i = 0; i < 8; ++i) e[i] = f2bf(tile[kc * 8 + i][nrow]);
    uint4 o;
    o.x = e[0] | (e[1] << 16); o.y = e[2] | (e[3] << 16);
    o.z = e[4] | (e[5] << 16); o.w = e[6] | (e[7] << 16);
    *(uint4*)(dst + (size_t)(n0 + nrow) * 1024 + k0 + kc * 8) = o;
  }
}

// ---------------------------------------------------------------------------
// Kernel 2: QKV projection. C = A(fp32)[8192,1024] @ W(via WT bf16).  z selects.
// 128x128 tile, BK=32, 4 waves. Epilogue scatters to Q/K (b,h,t,d) and V^T (b,h,d,t).
__global__ __launch_bounds__(256) void proj_gemm(const float* __restrict__ Xq,
                                                 const float* __restrict__ Xk,
                                                 const float* __restrict__ Xv,
                                                 const unsigned short* __restrict__ WT,
                                                 unsigned short* __restrict__ Qb,
                                                 unsigned short* __restrict__ Kb,
                                                 unsigned short* __restrict__ VTb) {
  int z = blockIdx.z;
  const float* A = (z == 0) ? Xq : (z == 1) ? Xk : Xv;
  const unsigned short* Bt = WT + (size_t)z * 1024 * 1024;
  int m0 = blockIdx.x * 128, n0 = blockIdx.y * 128;
  __shared__ __align__(16) unsigned short As[128 * 40];  // +8 pad rows (bank spread)
  __shared__ __align__(16) unsigned short Bs[128 * 32];  // linear (global_load_lds), xor-4 swz
  int tid = threadIdx.x, w = tid >> 6, lane = tid & 63;
  int lr = lane & 15, lg = lane >> 4;
  int wm = w >> 1, wn = w & 1;
  f32x4 acc[4][4];
#pragma unroll
  for (int i = 0; i < 4; ++i)
#pragma unroll
    for (int j = 0; j < 4; ++j) acc[i][j] = (f32x4){0.f, 0.f, 0.f, 0.f};

  for (int k0 = 0; k0 < 1024; k0 += 32) {
    // stage A: fp32 -> bf16 via regs
#pragma unroll
    for (int j = 0; j < 4; ++j) {
      int u = tid + j * 256;          // 1024 units: row 0..127, 8 float4 per row
      int row = u >> 3, sl = u & 7;
      float4 v = *(const float4*)(A + (size_t)(m0 + row) * 1024 + k0 + sl * 4);
      unsigned lo = f2bf(v.x) | ((unsigned)f2bf(v.y) << 16);
      unsigned hi = f2bf(v.z) | ((unsigned)f2bf(v.w) << 16);
      *(uint2*)(&As[row * 40 + sl * 4]) = make_uint2(lo, hi);
    }
    // stage B^T: global_load_lds, pre-swizzled source (xor-4 within 64B row)
#pragma unroll
    for (int c = 0; c < 2; ++c) {
      int base = c * 256 + w * 64;
      int u = base + lane;
      int row = u >> 2, sl = u & 3;
      int ssl = sl ^ (row & 3);
      gl_lds16(Bt + (size_t)(n0 + row) * 1024 + k0 + ssl * 8, &Bs[base * 8]);
    }
    __syncthreads();
    short8 af[4], bfr[4];
#pragma unroll
    for (int mi = 0; mi < 4; ++mi) {
      int row = wm * 64 + mi * 16 + lr;
      af[mi] = *(const short8*)(&As[row * 40 + lg * 8]);
    }
#pragma unroll
    for (int ni = 0; ni < 4; ++ni) {
      int row = wn * 64 + ni * 16 + lr;
      bfr[ni] = *(const short8*)(&Bs[(row * 4 + (lg ^ (row & 3))) * 8]);
    }
#pragma unroll
    for (int mi = 0; mi < 4; ++mi)
#pragma unroll
      for (int ni = 0; ni < 4; ++ni)
        acc[mi][ni] = __builtin_amdgcn_mfma_f32_16x16x32_bf16(af[mi], bfr[ni], acc[mi][ni], 0, 0, 0);
    __syncthreads();
  }
  // epilogue
#pragma unroll
  for (int mi = 0; mi < 4; ++mi)
#pragma unroll
    for (int ni = 0; ni < 4; ++ni)
#pragma unroll
      for (int r = 0; r < 4; ++r) {
        int m = m0 + wm * 64 + mi * 16 + lg * 4 + r;
        int n = n0 + wn * 64 + ni * 16 + lr;
        unsigned short cb = f2bf(acc[mi][ni][r]);
        int b = m >> 11, t = m & 2047;
        int h = n >> 6, d = n & 63;
        if (z == 0)
          Qb[((size_t)(b * 16 + h) * 2048 + t) * 64 + d] = cb;
        else if (z == 1)
          Kb[((size_t)(b * 16 + h) * 2048 + t) * 64 + d] = cb;
        else
          VTb[((size_t)(b * 16 + h) * 64 + d) * 2048 + t] = cb;
      }
}

// ---------------------------------------------------------------------------
// Kernel 3: causal flash attention.  grid (64 bh, 32 qblk) block 256 (4 waves x 16 q-rows).
// Swapped QK^T (mfma(K,Q) -> S^T): each lane owns q-row = lane&15 -> cheap row softmax.
__global__ __launch_bounds__(256) void attn_kernel(const unsigned short* __restrict__ Qb,
                                                   const unsigned short* __restrict__ Kb,
                                                   const unsigned short* __restrict__ VTb,
                                                   const int* __restrict__ qpm,
                                                   const int* __restrict__ kpm,
                                                   unsigned short* __restrict__ Ob) {
  int bh = blockIdx.x;
  int qi = (int)gridDim.y - 1 - (int)blockIdx.y;  // heavy (long) blocks dispatch first
  int b = bh >> 4, h = bh & 15;
  int q0 = qi * 64;
  int tid = threadIdx.x, w = tid >> 6, lane = tid & 63;
  int lr = lane & 15, lg = lane >> 4;
  __shared__ __align__(16) unsigned short Ks[64 * 72];     // K[kv][d], +8 pad
  __shared__ __align__(16) unsigned short Vs[64 * 72];     // V^T[d][kv], +8 pad
  __shared__ __align__(16) unsigned short Ps[4][16 * 72];  // per-wave P[q][kv], +8 pad

  int qrow = q0 + w * 16 + lr;  // this lane's q-row (S^T column)
  const unsigned short* qp = Qb + ((size_t)bh * 2048 + qrow) * 64 + lg * 8;
  short8 qf0 = *(const short8*)qp;
  short8 qf1 = *(const short8*)(qp + 32);
  const unsigned short* Kbh = Kb + (size_t)bh * 2048 * 64;
  const unsigned short* Vbh = VTb + (size_t)bh * 64 * 2048;

  f32x4 o[4];
#pragma unroll
  for (int dt = 0; dt < 4; ++dt) o[dt] = (f32x4){0.f, 0.f, 0.f, 0.f};
  float m_run = -1e30f, l_run = 0.f;
  const float CS = 0.125f * 1.44269504f;  // (1/sqrt(Dh)) * log2(e)

  int kv_end = q0 + 64;
  for (int kv0 = 0; kv0 < kv_end; kv0 += 64) {
    __syncthreads();  // prev-iter LDS reads done before overwrite
#pragma unroll
    for (int j = 0; j < 2; ++j) {
      int u = tid + j * 256;  // 512 units each for K and V^T
      int row = u >> 3, sl = u & 7;
      *(uint4*)(&Ks[row * 72 + sl * 8]) = *(const uint4*)(Kbh + (size_t)(kv0 + row) * 64 + sl * 8);
      *(uint4*)(&Vs[row * 72 + sl * 8]) = *(const uint4*)(Vbh + (size_t)row * 2048 + kv0 + sl * 8);
    }
    unsigned long long kmask = __ballot(kpm[b * 2048 + kv0 + lane] != 0);
    __syncthreads();

    // S^T = K·Q^T  (4 kv-strips of 16)
    float s[16];
#pragma unroll
    for (int t = 0; t < 4; ++t) {
      short8 kf0 = *(const short8*)(&Ks[(t * 16 + lr) * 72 + lg * 8]);
      short8 kf1 = *(const short8*)(&Ks[(t * 16 + lr) * 72 + 32 + lg * 8]);
      f32x4 sa = (f32x4){0.f, 0.f, 0.f, 0.f};
      sa = __builtin_amdgcn_mfma_f32_16x16x32_bf16(kf0, qf0, sa, 0, 0, 0);
      sa = __builtin_amdgcn_mfma_f32_16x16x32_bf16(kf1, qf1, sa, 0, 0, 0);
#pragma unroll
      for (int r = 0; r < 4; ++r) {
        int kvl = t * 16 + lg * 4 + r;
        int kvg = kv0 + kvl;
        bool ok = (kvg <= qrow) && ((kmask >> kvl) & 1ull);
        s[t * 4 + r] = ok ? sa[r] : -1e30f;
      }
    }
    // online softmax over kv for q-row = lr
    float pm = s[0];
#pragma unroll
    for (int i = 1; i < 16; ++i) pm = fmaxf(pm, s[i]);
    pm = fmaxf(pm, __shfl_xor(pm, 16));
    pm = fmaxf(pm, __shfl_xor(pm, 32));
    float mnew = fmaxf(m_run, pm);
    float fs = exp2f((m_run - mnew) * CS);
    float p[16], ps = 0.f;
#pragma unroll
    for (int i = 0; i < 16; ++i) {
      p[i] = exp2f((s[i] - mnew) * CS);
      ps += p[i];
    }
    ps += __shfl_xor(ps, 16);
    ps += __shfl_xor(ps, 32);
    l_run = l_run * fs + ps;
    m_run = mnew;
    // rescale O (O rows: q = lg*4+r -> fetch fs from lane owning that q)
    float f4[4];
#pragma unroll
    for (int r = 0; r < 4; ++r) f4[r] = __shfl(fs, lg * 4 + r);
#pragma unroll
    for (int dt = 0; dt < 4; ++dt)
#pragma unroll
      for (int r = 0; r < 4; ++r) o[dt][r] *= f4[r];
    // P -> LDS (packed b64, row q=lr, kv = t*16+lg*4..+4)
#pragma unroll
    for (int t = 0; t < 4; ++t) {
      unsigned lo = f2bf(p[t * 4 + 0]) | ((unsigned)f2bf(p[t * 4 + 1]) << 16);
      unsigned hi = f2bf(p[t * 4 + 2]) | ((unsigned)f2bf(p[t * 4 + 3]) << 16);
      *(uint2*)(&Ps[w][lr * 72 + t * 16 + lg * 4]) = make_uint2(lo, hi);
    }
    // PV: O[q][d] += P[q][kv] V[kv][d]   (in-wave LDS RAW: DS pipe is in-order)
#pragma unroll
    for (int st = 0; st < 2; ++st) {
      short8 pa = *(const short8*)(&Ps[w][lr * 72 + st * 32 + lg * 8]);
#pragma unroll
      for (int dt = 0; dt < 4; ++dt) {
        short8 vf = *(const short8*)(&Vs[(dt * 16 + lr) * 72 + st * 32 + lg * 8]);
        o[dt] = __builtin_amdgcn_mfma_f32_16x16x32_bf16(pa, vf, o[dt], 0, 0, 0);
      }
    }
  }
  // epilogue: /l, *query_mask, write bf16 [8192][1024]
  float l4[4], qm4[4];
#pragma unroll
  for (int r = 0; r < 4; ++r) {
    l4[r] = __shfl(l_run, lg * 4 + r);
    int qg = q0 + w * 16 + lg * 4 + r;
    qm4[r] = (qpm[b * 2048 + qg] != 0) ? 1.f : 0.f;
  }
#pragma unroll
  for (int dt = 0; dt < 4; ++dt)
#pragma unroll
    for (int r = 0; r < 4; ++r) {
      int qg = q0 + w * 16 + lg * 4 + r;
      float val = o[dt][r] * qm4[r] / l4[r];
      Ob[(size_t)(b * 2048 + qg) * 1024 + h * 64 + dt * 16 + lr] = f2bf(val);
    }
}

// ---------------------------------------------------------------------------
// Kernel 4: output projection. C(fp32) = Ob(bf16)[8192,1024] @ Wo (via WoT bf16).
__global__ __launch_bounds__(256) void out_gemm(const unsigned short* __restrict__ Ab,
                                                const unsigned short* __restrict__ WoT,
                                                float* __restrict__ C) {
  int m0 = blockIdx.x * 128, n0 = blockIdx.y * 128;
  __shared__ __align__(16) unsigned short As[128 * 32];
  __shared__ __align__(16) unsigned short Bs[128 * 32];
  int tid = threadIdx.x, w = tid >> 6, lane = tid & 63;
  int lr = lane & 15, lg = lane >> 4;
  int wm = w >> 1, wn = w & 1;
  f32x4 acc[4][4];
#pragma unroll
  for (int i = 0; i < 4; ++i)
#pragma unroll
    for (int j = 0; j < 4; ++j) acc[i][j] = (f32x4){0.f, 0.f, 0.f, 0.f};

  for (int k0 = 0; k0 < 1024; k0 += 32) {
#pragma unroll
    for (int c = 0; c < 2; ++c) {
      int base = c * 256 + w * 64;
      int u = base + lane;
      int row = u >> 2, sl = u & 3;
      int ssl = sl ^ (row & 3);
      gl_lds16(Ab + (size_t)(m0 + row) * 1024 + k0 + ssl * 8, &As[base * 8]);
      gl_lds16(WoT + (size_t)(n0 + row) * 1024 + k0 + ssl * 8, &Bs[base * 8]);
    }
    __syncthreads();
    short8 af[4], bfr[4];
#pragma unroll
    for (int mi = 0; mi < 4; ++mi) {
      int row = wm * 64 + mi * 16 + lr;
      af[mi] = *(const short8*)(&As[(row * 4 + (lg ^ (row & 3))) * 8]);
    }
#pragma unroll
    for (int ni = 0; ni < 4; ++ni) {
      int row = wn * 64 + ni * 16 + lr;
      bfr[ni] = *(const short8*)(&Bs[(row * 4 + (lg ^ (row & 3))) * 8]);
    }
#pragma unroll
    for (int mi = 0; mi < 4; ++mi)
#pragma unroll
      for (int ni = 0; ni < 4; ++ni)
        acc[mi][ni] = __builtin_amdgcn_mfma_f32_16x16x32_bf16(af[mi], bfr[ni], acc[mi][ni], 0, 0, 0);
    __syncthreads();
  }
#pragma unroll
  for (int mi = 0; mi < 4; ++mi)
#pragma unroll
    for (int ni = 0; ni < 4; ++ni)
#pragma unroll
      for (int r = 0; r < 4; ++r) {
        int m = m0 + wm * 64 + mi * 16 + lg * 4 + r;
        int n = n0 + wn * 64 + ni * 16 + lr;
        C[(size_t)m * 1024 + n] = acc[mi][ni][r];
      }
}

// ---------------------------------------------------------------------------
extern "C" void kernel_launch(void* const* d_in, const int* in_sizes, int n_in,
                              void* d_out, int out_size, void* d_ws, size_t ws_size,
                              hipStream_t stream) {
  const float* q = (const float*)d_in[0];
  const float* k = (const float*)d_in[1];
  const float* v = (const float*)d_in[2];
  const int* qpm = (const int*)d_in[3];
  const int* kpm = (const int*)d_in[4];
  const float* Wq = (const float*)d_in[5];
  const float* Wk = (const float*)d_in[6];
  const float* Wv = (const float*)d_in[7];
  const float* Wo = (const float*)d_in[8];
  float* out = (float*)d_out;

  char* ws = (char*)d_ws;  // needs 72 MB
  unsigned short* WT  = (unsigned short*)(ws);                      // 4x1M bf16 (8 MB)
  unsigned short* Qb  = (unsigned short*)(ws + ((size_t)8 << 20));  // 16 MB
  unsigned short* Kb  = (unsigned short*)(ws + ((size_t)24 << 20)); // 16 MB
  unsigned short* VTb = (unsigned short*)(ws + ((size_t)40 << 20)); // 16 MB
  unsigned short* Ob  = (unsigned short*)(ws + ((size_t)56 << 20)); // 16 MB

  prep_w<<<dim3(16, 16, 4), 256, 0, stream>>>(Wq, Wk, Wv, Wo, WT);
  proj_gemm<<<dim3(64, 8, 3), 256, 0, stream>>>(q, k, v, WT, Qb, Kb, VTb);
  attn_kernel<<<dim3(64, 32), 256, 0, stream>>>(Qb, Kb, VTb, qpm, kpm, Ob);
  out_gemm<<<dim3(64, 8), 256, 0, stream>>>(Ob, WT + (size_t)3 * 1024 * 1024, out);
}

// Round 5
// 378.818 us; speedup vs baseline: 1.0318x; 1.0318x over previous
//
#include <hip/hip_runtime.h>
#include <hip/hip_bf16.h>
#include <stdint.h>

// MHA: B=4, T=2048, D=1024, H=16, Dh=64.  All MFMA in bf16 (16x16x32), fp32 accum.
// Pipeline: prep_w (W->W^T bf16) ; prep_x (X fp32->bf16) ; proj_gemm (Q,K,V^T bf16) ;
// attn (flash, causal) ; out_gemm (-> fp32 d_out).
// Workspace layout (104 MB):
//   WT  = ws+0     (8 MB, 4x [1024][1024] bf16)
//   Xb  = ws+8M    (48 MB, 3x [8192][1024] bf16)       -- dead after proj_gemm
//   Ob  = ws+8M    (16 MB, aliases Xb[0:16M]; live attn->out_gemm)
//   Qb  = ws+56M, Kb = ws+72M, VTb = ws+88M  (16 MB each)

typedef __attribute__((ext_vector_type(8))) short short8;   // 8 x bf16 = 4 VGPR (MFMA A/B frag)
typedef __attribute__((ext_vector_type(4))) float f32x4;    // MFMA C/D frag

__device__ __forceinline__ unsigned short f2bf(float f) {
  union { float f; unsigned u; } v; v.f = f;
  unsigned r = (v.u + 0x7fffu + ((v.u >> 16) & 1u)) >> 16;
  return (unsigned short)r;
}

__device__ __forceinline__ void gl_lds16(const void* g, void* l) {
  __builtin_amdgcn_global_load_lds((const __attribute__((address_space(1))) void*)g,
                                   (__attribute__((address_space(3))) void*)l, 16, 0, 0);
}

// ---------------------------------------------------------------------------
// Kernel 1: transpose+convert weights. W[k][n] fp32 -> WT[n][k] bf16.
__global__ __launch_bounds__(256) void prep_w(const float* __restrict__ Wq,
                                              const float* __restrict__ Wk,
                                              const float* __restrict__ Wv,
                                              const float* __restrict__ Wo,
                                              unsigned short* __restrict__ WT) {
  int z = blockIdx.z;
  const float* W = (z == 0) ? Wq : (z == 1) ? Wk : (z == 2) ? Wv : Wo;
  unsigned short* dst = WT + (size_t)z * 1024 * 1024;
  int k0 = blockIdx.x * 64, n0 = blockIdx.y * 64;
  __shared__ float tile[64][65];
  int tid = threadIdx.x;
#pragma unroll
  for (int j = 0; j < 4; ++j) {
    int u = tid + j * 256;            // 1024 units of float4
    int row = u >> 4, c4 = u & 15;
    float4 v = *(const float4*)(W + (size_t)(k0 + row) * 1024 + n0 + c4 * 4);
    tile[row][c4 * 4 + 0] = v.x;
    tile[row][c4 * 4 + 1] = v.y;
    tile[row][c4 * 4 + 2] = v.z;
    tile[row][c4 * 4 + 3] = v.w;
  }
  __syncthreads();
#pragma unroll
  for (int j = 0; j < 2; ++j) {
    int u = tid + j * 256;            // 512 units of 8 bf16
    int nrow = u >> 3, kc = u & 7;
    unsigned e[8];
#pragma unroll
    for (int i = 0; i < 8; ++i) e[i] = f2bf(tile[kc * 8 + i][nrow]);
    uint4 o;
    o.x = e[0] | (e[1] << 16); o.y = e[2] | (e[3] << 16);
    o.z = e[4] | (e[5] << 16); o.w = e[6] | (e[7] << 16);
    *(uint4*)(dst + (size_t)(n0 + nrow) * 1024 + k0 + kc * 8) = o;
  }
}

// ---------------------------------------------------------------------------
// Kernel 1b: X fp32 -> bf16 (row-major copy). grid (4096,1,3), 8 elems/thread.
__global__ __launch_bounds__(256) void prep_x(const float* __restrict__ Xq,
                                              const float* __restrict__ Xk,
                                              const float* __restrict__ Xv,
                                              unsigned short* __restrict__ Xb) {
  int z = blockIdx.z;
  const float* src = (z == 0) ? Xq : (z == 1) ? Xk : Xv;
  unsigned short* dst = Xb + (size_t)z * 8388608;
  size_t i0 = ((size_t)blockIdx.x * 256 + threadIdx.x) * 8;
  float4 a = *(const float4*)(src + i0);
  float4 b = *(const float4*)(src + i0 + 4);
  uint4 o;
  o.x = f2bf(a.x) | ((unsigned)f2bf(a.y) << 16);
  o.y = f2bf(a.z) | ((unsigned)f2bf(a.w) << 16);
  o.z = f2bf(b.x) | ((unsigned)f2bf(b.y) << 16);
  o.w = f2bf(b.z) | ((unsigned)f2bf(b.w) << 16);
  *(uint4*)(dst + i0) = o;
}

// ---------------------------------------------------------------------------
// Kernel 2: QKV projection, all-bf16. C = Xb[8192,1024] @ W (via WT).  z selects.
// 128x128 tile, BK=32, 4 waves, both operands via global_load_lds (xor-4 swizzle).
// Epilogue scatters to Q/K (b,h,t,d) and V^T (b,h,d,t).
__global__ __launch_bounds__(256) void proj_gemm(const unsigned short* __restrict__ Xb,
                                                 const unsigned short* __restrict__ WT,
                                                 unsigned short* __restrict__ Qb,
                                                 unsigned short* __restrict__ Kb,
                                                 unsigned short* __restrict__ VTb) {
  int z = blockIdx.z;
  const unsigned short* A = Xb + (size_t)z * 8388608;
  const unsigned short* Bt = WT + (size_t)z * 1024 * 1024;
  int m0 = blockIdx.x * 128, n0 = blockIdx.y * 128;
  __shared__ __align__(16) unsigned short As[128 * 32];
  __shared__ __align__(16) unsigned short Bs[128 * 32];
  int tid = threadIdx.x, w = tid >> 6, lane = tid & 63;
  int lr = lane & 15, lg = lane >> 4;
  int wm = w >> 1, wn = w & 1;
  f32x4 acc[4][4];
#pragma unroll
  for (int i = 0; i < 4; ++i)
#pragma unroll
    for (int j = 0; j < 4; ++j) acc[i][j] = (f32x4){0.f, 0.f, 0.f, 0.f};

  for (int k0 = 0; k0 < 1024; k0 += 32) {
#pragma unroll
    for (int c = 0; c < 2; ++c) {
      int base = c * 256 + w * 64;
      int u = base + lane;
      int row = u >> 2, sl = u & 3;
      int ssl = sl ^ (row & 3);
      gl_lds16(A + (size_t)(m0 + row) * 1024 + k0 + ssl * 8, &As[base * 8]);
      gl_lds16(Bt + (size_t)(n0 + row) * 1024 + k0 + ssl * 8, &Bs[base * 8]);
    }
    __syncthreads();
    short8 af[4], bfr[4];
#pragma unroll
    for (int mi = 0; mi < 4; ++mi) {
      int row = wm * 64 + mi * 16 + lr;
      af[mi] = *(const short8*)(&As[(row * 4 + (lg ^ (row & 3))) * 8]);
    }
#pragma unroll
    for (int ni = 0; ni < 4; ++ni) {
      int row = wn * 64 + ni * 16 + lr;
      bfr[ni] = *(const short8*)(&Bs[(row * 4 + (lg ^ (row & 3))) * 8]);
    }
#pragma unroll
    for (int mi = 0; mi < 4; ++mi)
#pragma unroll
      for (int ni = 0; ni < 4; ++ni)
        acc[mi][ni] = __builtin_amdgcn_mfma_f32_16x16x32_bf16(af[mi], bfr[ni], acc[mi][ni], 0, 0, 0);
    __syncthreads();
  }
  // epilogue
#pragma unroll
  for (int mi = 0; mi < 4; ++mi)
#pragma unroll
    for (int ni = 0; ni < 4; ++ni)
#pragma unroll
      for (int r = 0; r < 4; ++r) {
        int m = m0 + wm * 64 + mi * 16 + lg * 4 + r;
        int n = n0 + wn * 64 + ni * 16 + lr;
        unsigned short cb = f2bf(acc[mi][ni][r]);
        int b = m >> 11, t = m & 2047;
        int h = n >> 6, d = n & 63;
        if (z == 0)
          Qb[((size_t)(b * 16 + h) * 2048 + t) * 64 + d] = cb;
        else if (z == 1)
          Kb[((size_t)(b * 16 + h) * 2048 + t) * 64 + d] = cb;
        else
          VTb[((size_t)(b * 16 + h) * 64 + d) * 2048 + t] = cb;
      }
}

// ---------------------------------------------------------------------------
// Kernel 3: causal flash attention.  grid (64 bh, 32 qblk) block 256 (4 waves x 16 q-rows).
// Swapped QK^T (mfma(K,Q) -> S^T): each lane owns q-row = lane&15 -> cheap row softmax.
__global__ __launch_bounds__(256) void attn_kernel(const unsigned short* __restrict__ Qb,
                                                   const unsigned short* __restrict__ Kb,
                                                   const unsigned short* __restrict__ VTb,
                                                   const int* __restrict__ qpm,
                                                   const int* __restrict__ kpm,
                                                   unsigned short* __restrict__ Ob) {
  int bh = blockIdx.x;
  int qi = (int)gridDim.y - 1 - (int)blockIdx.y;  // heavy (long) blocks dispatch first
  int b = bh >> 4, h = bh & 15;
  int q0 = qi * 64;
  int tid = threadIdx.x, w = tid >> 6, lane = tid & 63;
  int lr = lane & 15, lg = lane >> 4;
  __shared__ __align__(16) unsigned short Ks[64 * 72];     // K[kv][d], +8 pad
  __shared__ __align__(16) unsigned short Vs[64 * 72];     // V^T[d][kv], +8 pad
  __shared__ __align__(16) unsigned short Ps[4][16 * 72];  // per-wave P[q][kv], +8 pad

  int qrow = q0 + w * 16 + lr;  // this lane's q-row (S^T column)
  const unsigned short* qp = Qb + ((size_t)bh * 2048 + qrow) * 64 + lg * 8;
  short8 qf0 = *(const short8*)qp;
  short8 qf1 = *(const short8*)(qp + 32);
  const unsigned short* Kbh = Kb + (size_t)bh * 2048 * 64;
  const unsigned short* Vbh = VTb + (size_t)bh * 64 * 2048;

  f32x4 o[4];
#pragma unroll
  for (int dt = 0; dt < 4; ++dt) o[dt] = (f32x4){0.f, 0.f, 0.f, 0.f};
  float m_run = -1e30f, l_run = 0.f;
  const float CS = 0.125f * 1.44269504f;  // (1/sqrt(Dh)) * log2(e)

  int kv_end = q0 + 64;
  for (int kv0 = 0; kv0 < kv_end; kv0 += 64) {
    __syncthreads();  // prev-iter LDS reads done before overwrite
#pragma unroll
    for (int j = 0; j < 2; ++j) {
      int u = tid + j * 256;  // 512 units each for K and V^T
      int row = u >> 3, sl = u & 7;
      *(uint4*)(&Ks[row * 72 + sl * 8]) = *(const uint4*)(Kbh + (size_t)(kv0 + row) * 64 + sl * 8);
      *(uint4*)(&Vs[row * 72 + sl * 8]) = *(const uint4*)(Vbh + (size_t)row * 2048 + kv0 + sl * 8);
    }
    unsigned long long kmask = __ballot(kpm[b * 2048 + kv0 + lane] != 0);
    __syncthreads();

    // S^T = K·Q^T  (4 kv-strips of 16)
    float s[16];
#pragma unroll
    for (int t = 0; t < 4; ++t) {
      short8 kf0 = *(const short8*)(&Ks[(t * 16 + lr) * 72 + lg * 8]);
      short8 kf1 = *(const short8*)(&Ks[(t * 16 + lr) * 72 + 32 + lg * 8]);
      f32x4 sa = (f32x4){0.f, 0.f, 0.f, 0.f};
      sa = __builtin_amdgcn_mfma_f32_16x16x32_bf16(kf0, qf0, sa, 0, 0, 0);
      sa = __builtin_amdgcn_mfma_f32_16x16x32_bf16(kf1, qf1, sa, 0, 0, 0);
#pragma unroll
      for (int r = 0; r < 4; ++r) {
        int kvl = t * 16 + lg * 4 + r;
        int kvg = kv0 + kvl;
        bool ok = (kvg <= qrow) && ((kmask >> kvl) & 1ull);
        s[t * 4 + r] = ok ? sa[r] : -1e30f;
      }
    }
    // online softmax over kv for q-row = lr
    float pm = s[0];
#pragma unroll
    for (int i = 1; i < 16; ++i) pm = fmaxf(pm, s[i]);
    pm = fmaxf(pm, __shfl_xor(pm, 16));
    pm = fmaxf(pm, __shfl_xor(pm, 32));
    float mnew = fmaxf(m_run, pm);
    float fs = exp2f((m_run - mnew) * CS);
    float p[16], ps = 0.f;
#pragma unroll
    for (int i = 0; i < 16; ++i) {
      p[i] = exp2f((s[i] - mnew) * CS);
      ps += p[i];
    }
    ps += __shfl_xor(ps, 16);
    ps += __shfl_xor(ps, 32);
    l_run = l_run * fs + ps;
    m_run = mnew;
    // rescale O (O rows: q = lg*4+r -> fetch fs from lane owning that q)
    float f4[4];
#pragma unroll
    for (int r = 0; r < 4; ++r) f4[r] = __shfl(fs, lg * 4 + r);
#pragma unroll
    for (int dt = 0; dt < 4; ++dt)
#pragma unroll
      for (int r = 0; r < 4; ++r) o[dt][r] *= f4[r];
    // P -> LDS (packed b64, row q=lr, kv = t*16+lg*4..+4)
#pragma unroll
    for (int t = 0; t < 4; ++t) {
      unsigned lo = f2bf(p[t * 4 + 0]) | ((unsigned)f2bf(p[t * 4 + 1]) << 16);
      unsigned hi = f2bf(p[t * 4 + 2]) | ((unsigned)f2bf(p[t * 4 + 3]) << 16);
      *(uint2*)(&Ps[w][lr * 72 + t * 16 + lg * 4]) = make_uint2(lo, hi);
    }
    // PV: O[q][d] += P[q][kv] V[kv][d]   (in-wave LDS RAW: DS pipe is in-order)
#pragma unroll
    for (int st = 0; st < 2; ++st) {
      short8 pa = *(const short8*)(&Ps[w][lr * 72 + st * 32 + lg * 8]);
#pragma unroll
      for (int dt = 0; dt < 4; ++dt) {
        short8 vf = *(const short8*)(&Vs[(dt * 16 + lr) * 72 + st * 32 + lg * 8]);
        o[dt] = __builtin_amdgcn_mfma_f32_16x16x32_bf16(pa, vf, o[dt], 0, 0, 0);
      }
    }
  }
  // epilogue: /l, *query_mask, write bf16 [8192][1024]
  float l4[4], qm4[4];
#pragma unroll
  for (int r = 0; r < 4; ++r) {
    l4[r] = __shfl(l_run, lg * 4 + r);
    int qg = q0 + w * 16 + lg * 4 + r;
    qm4[r] = (qpm[b * 2048 + qg] != 0) ? 1.f : 0.f;
  }
#pragma unroll
  for (int dt = 0; dt < 4; ++dt)
#pragma unroll
    for (int r = 0; r < 4; ++r) {
      int qg = q0 + w * 16 + lg * 4 + r;
      float val = o[dt][r] * qm4[r] / l4[r];
      Ob[(size_t)(b * 2048 + qg) * 1024 + h * 64 + dt * 16 + lr] = f2bf(val);
    }
}

// ---------------------------------------------------------------------------
// Kernel 4: output projection. C(fp32) = Ob(bf16)[8192,1024] @ Wo (via WoT bf16).
__global__ __launch_bounds__(256) void out_gemm(const unsigned short* __restrict__ Ab,
                                                const unsigned short* __restrict__ WoT,
                                                float* __restrict__ C) {
  int m0 = blockIdx.x * 128, n0 = blockIdx.y * 128;
  __shared__ __align__(16) unsigned short As[128 * 32];
  __shared__ __align__(16) unsigned short Bs[128 * 32];
  int tid = threadIdx.x, w = tid >> 6, lane = tid & 63;
  int lr = lane & 15, lg = lane >> 4;
  int wm = w >> 1, wn = w & 1;
  f32x4 acc[4][4];
#pragma unroll
  for (int i = 0; i < 4; ++i)
#pragma unroll
    for (int j = 0; j < 4; ++j) acc[i][j] = (f32x4){0.f, 0.f, 0.f, 0.f};

  for (int k0 = 0; k0 < 1024; k0 += 32) {
#pragma unroll
    for (int c = 0; c < 2; ++c) {
      int base = c * 256 + w * 64;
      int u = base + lane;
      int row = u >> 2, sl = u & 3;
      int ssl = sl ^ (row & 3);
      gl_lds16(Ab + (size_t)(m0 + row) * 1024 + k0 + ssl * 8, &As[base * 8]);
      gl_lds16(WoT + (size_t)(n0 + row) * 1024 + k0 + ssl * 8, &Bs[base * 8]);
    }
    __syncthreads();
    short8 af[4], bfr[4];
#pragma unroll
    for (int mi = 0; mi < 4; ++mi) {
      int row = wm * 64 + mi * 16 + lr;
      af[mi] = *(const short8*)(&As[(row * 4 + (lg ^ (row & 3))) * 8]);
    }
#pragma unroll
    for (int ni = 0; ni < 4; ++ni) {
      int row = wn * 64 + ni * 16 + lr;
      bfr[ni] = *(const short8*)(&Bs[(row * 4 + (lg ^ (row & 3))) * 8]);
    }
#pragma unroll
    for (int mi = 0; mi < 4; ++mi)
#pragma unroll
      for (int ni = 0; ni < 4; ++ni)
        acc[mi][ni] = __builtin_amdgcn_mfma_f32_16x16x32_bf16(af[mi], bfr[ni], acc[mi][ni], 0, 0, 0);
    __syncthreads();
  }
#pragma unroll
  for (int mi = 0; mi < 4; ++mi)
#pragma unroll
    for (int ni = 0; ni < 4; ++ni)
#pragma unroll
      for (int r = 0; r < 4; ++r) {
        int m = m0 + wm * 64 + mi * 16 + lg * 4 + r;
        int n = n0 + wn * 64 + ni * 16 + lr;
        C[(size_t)m * 1024 + n] = acc[mi][ni][r];
      }
}

// ---------------------------------------------------------------------------
extern "C" void kernel_launch(void* const* d_in, const int* in_sizes, int n_in,
                              void* d_out, int out_size, void* d_ws, size_t ws_size,
                              hipStream_t stream) {
  const float* q = (const float*)d_in[0];
  const float* k = (const float*)d_in[1];
  const float* v = (const float*)d_in[2];
  const int* qpm = (const int*)d_in[3];
  const int* kpm = (const int*)d_in[4];
  const float* Wq = (const float*)d_in[5];
  const float* Wk = (const float*)d_in[6];
  const float* Wv = (const float*)d_in[7];
  const float* Wo = (const float*)d_in[8];
  float* out = (float*)d_out;

  char* ws = (char*)d_ws;  // needs 104 MB
  unsigned short* WT  = (unsigned short*)(ws);                       // 8 MB
  unsigned short* Xb  = (unsigned short*)(ws + ((size_t)8 << 20));   // 48 MB (dead after proj)
  unsigned short* Ob  = (unsigned short*)(ws + ((size_t)8 << 20));   // 16 MB (aliases Xb; live attn->out)
  unsigned short* Qb  = (unsigned short*)(ws + ((size_t)56 << 20));  // 16 MB
  unsigned short* Kb  = (unsigned short*)(ws + ((size_t)72 << 20));  // 16 MB
  unsigned short* VTb = (unsigned short*)(ws + ((size_t)88 << 20));  // 16 MB

  prep_w<<<dim3(16, 16, 4), 256, 0, stream>>>(Wq, Wk, Wv, Wo, WT);
  prep_x<<<dim3(4096, 1, 3), 256, 0, stream>>>(q, k, v, Xb);
  proj_gemm<<<dim3(64, 8, 3), 256, 0, stream>>>(Xb, WT, Qb, Kb, VTb);
  attn_kernel<<<dim3(64, 32), 256, 0, stream>>>(Qb, Kb, VTb, qpm, kpm, Ob);
  out_gemm<<<dim3(64, 8), 256, 0, stream>>>(Ob, WT + (size_t)3 * 1024 * 1024, out);
}

// Round 6
// 363.406 us; speedup vs baseline: 1.0756x; 1.0424x over previous
//
#include <hip/hip_runtime.h>
#include <hip/hip_bf16.h>
#include <stdint.h>

// MHA: B=4, T=2048, D=1024, H=16, Dh=64.  All MFMA in bf16 (16x16x32), fp32 accum.
// Pipeline: prep_w (W->W^T bf16) ; prep_x (X fp32->bf16) ; proj_gemm (Q,K,V^T bf16) ;
// attn (flash, causal, QBLK=128) ; out_gemm (-> fp32 d_out).
// Workspace layout (104 MB):
//   WT  = ws+0     (8 MB)   Xb = ws+8M (48 MB, dead after proj; Ob aliases first 16 MB)
//   Qb  = ws+56M, Kb = ws+72M, VTb = ws+88M  (16 MB each)

typedef __attribute__((ext_vector_type(8))) short short8;   // 8 x bf16 = 4 VGPR (MFMA A/B frag)
typedef __attribute__((ext_vector_type(4))) float f32x4;    // MFMA C/D frag

__device__ __forceinline__ unsigned short f2bf(float f) {
  union { float f; unsigned u; } v; v.f = f;
  unsigned r = (v.u + 0x7fffu + ((v.u >> 16) & 1u)) >> 16;
  return (unsigned short)r;
}

__device__ __forceinline__ unsigned pk2(float a, float b) {
  __hip_bfloat162 h = __float22bfloat162_rn(make_float2(a, b));  // v_cvt_pk_bf16_f32
  union { __hip_bfloat162 h; unsigned u; } cv; cv.h = h;
  return cv.u;
}

#if __has_builtin(__builtin_amdgcn_exp2f)
#define EXP2(x) __builtin_amdgcn_exp2f(x)
#else
#define EXP2(x) exp2f(x)
#endif

__device__ __forceinline__ void gl_lds16(const void* g, void* l) {
  __builtin_amdgcn_global_load_lds((const __attribute__((address_space(1))) void*)g,
                                   (__attribute__((address_space(3))) void*)l, 16, 0, 0);
}

// ---------------------------------------------------------------------------
// Kernel 1: transpose+convert weights. W[k][n] fp32 -> WT[n][k] bf16.
__global__ __launch_bounds__(256) void prep_w(const float* __restrict__ Wq,
                                              const float* __restrict__ Wk,
                                              const float* __restrict__ Wv,
                                              const float* __restrict__ Wo,
                                              unsigned short* __restrict__ WT) {
  int z = blockIdx.z;
  const float* W = (z == 0) ? Wq : (z == 1) ? Wk : (z == 2) ? Wv : Wo;
  unsigned short* dst = WT + (size_t)z * 1024 * 1024;
  int k0 = blockIdx.x * 64, n0 = blockIdx.y * 64;
  __shared__ float tile[64][65];
  int tid = threadIdx.x;
#pragma unroll
  for (int j = 0; j < 4; ++j) {
    int u = tid + j * 256;
    int row = u >> 4, c4 = u & 15;
    float4 v = *(const float4*)(W + (size_t)(k0 + row) * 1024 + n0 + c4 * 4);
    tile[row][c4 * 4 + 0] = v.x;
    tile[row][c4 * 4 + 1] = v.y;
    tile[row][c4 * 4 + 2] = v.z;
    tile[row][c4 * 4 + 3] = v.w;
  }
  __syncthreads();
#pragma unroll
  for (int j = 0; j < 2; ++j) {
    int u = tid + j * 256;
    int nrow = u >> 3, kc = u & 7;
    unsigned e[8];
#pragma unroll
    for (int i = 0; i < 8; ++i) e[i] = f2bf(tile[kc * 8 + i][nrow]);
    uint4 o;
    o.x = e[0] | (e[1] << 16); o.y = e[2] | (e[3] << 16);
    o.z = e[4] | (e[5] << 16); o.w = e[6] | (e[7] << 16);
    *(uint4*)(dst + (size_t)(n0 + nrow) * 1024 + k0 + kc * 8) = o;
  }
}

// ---------------------------------------------------------------------------
// Kernel 1b: X fp32 -> bf16 (row-major copy). grid (4096,1,3), 8 elems/thread.
__global__ __launch_bounds__(256) void prep_x(const float* __restrict__ Xq,
                                              const float* __restrict__ Xk,
                                              const float* __restrict__ Xv,
                                              unsigned short* __restrict__ Xb) {
  int z = blockIdx.z;
  const float* src = (z == 0) ? Xq : (z == 1) ? Xk : Xv;
  unsigned short* dst = Xb + (size_t)z * 8388608;
  size_t i0 = ((size_t)blockIdx.x * 256 + threadIdx.x) * 8;
  float4 a = *(const float4*)(src + i0);
  float4 b = *(const float4*)(src + i0 + 4);
  uint4 o;
  o.x = f2bf(a.x) | ((unsigned)f2bf(a.y) << 16);
  o.y = f2bf(a.z) | ((unsigned)f2bf(a.w) << 16);
  o.z = f2bf(b.x) | ((unsigned)f2bf(b.y) << 16);
  o.w = f2bf(b.z) | ((unsigned)f2bf(b.w) << 16);
  *(uint4*)(dst + i0) = o;
}

// ---------------------------------------------------------------------------
// Kernel 2: QKV projection, all-bf16. 128x128 tile, BK=32, 4 waves.
__global__ __launch_bounds__(256) void proj_gemm(const unsigned short* __restrict__ Xb,
                                                 const unsigned short* __restrict__ WT,
                                                 unsigned short* __restrict__ Qb,
                                                 unsigned short* __restrict__ Kb,
                                                 unsigned short* __restrict__ VTb) {
  int z = blockIdx.z;
  const unsigned short* A = Xb + (size_t)z * 8388608;
  const unsigned short* Bt = WT + (size_t)z * 1024 * 1024;
  int m0 = blockIdx.x * 128, n0 = blockIdx.y * 128;
  __shared__ __align__(16) unsigned short As[128 * 32];
  __shared__ __align__(16) unsigned short Bs[128 * 32];
  int tid = threadIdx.x, w = tid >> 6, lane = tid & 63;
  int lr = lane & 15, lg = lane >> 4;
  int wm = w >> 1, wn = w & 1;
  f32x4 acc[4][4];
#pragma unroll
  for (int i = 0; i < 4; ++i)
#pragma unroll
    for (int j = 0; j < 4; ++j) acc[i][j] = (f32x4){0.f, 0.f, 0.f, 0.f};

  for (int k0 = 0; k0 < 1024; k0 += 32) {
#pragma unroll
    for (int c = 0; c < 2; ++c) {
      int base = c * 256 + w * 64;
      int u = base + lane;
      int row = u >> 2, sl = u & 3;
      int ssl = sl ^ (row & 3);
      gl_lds16(A + (size_t)(m0 + row) * 1024 + k0 + ssl * 8, &As[base * 8]);
      gl_lds16(Bt + (size_t)(n0 + row) * 1024 + k0 + ssl * 8, &Bs[base * 8]);
    }
    __syncthreads();
    short8 af[4], bfr[4];
#pragma unroll
    for (int mi = 0; mi < 4; ++mi) {
      int row = wm * 64 + mi * 16 + lr;
      af[mi] = *(const short8*)(&As[(row * 4 + (lg ^ (row & 3))) * 8]);
    }
#pragma unroll
    for (int ni = 0; ni < 4; ++ni) {
      int row = wn * 64 + ni * 16 + lr;
      bfr[ni] = *(const short8*)(&Bs[(row * 4 + (lg ^ (row & 3))) * 8]);
    }
#pragma unroll
    for (int mi = 0; mi < 4; ++mi)
#pragma unroll
      for (int ni = 0; ni < 4; ++ni)
        acc[mi][ni] = __builtin_amdgcn_mfma_f32_16x16x32_bf16(af[mi], bfr[ni], acc[mi][ni], 0, 0, 0);
    __syncthreads();
  }
#pragma unroll
  for (int mi = 0; mi < 4; ++mi)
#pragma unroll
    for (int ni = 0; ni < 4; ++ni)
#pragma unroll
      for (int r = 0; r < 4; ++r) {
        int m = m0 + wm * 64 + mi * 16 + lg * 4 + r;
        int n = n0 + wn * 64 + ni * 16 + lr;
        unsigned short cb = f2bf(acc[mi][ni][r]);
        int b = m >> 11, t = m & 2047;
        int h = n >> 6, d = n & 63;
        if (z == 0)
          Qb[((size_t)(b * 16 + h) * 2048 + t) * 64 + d] = cb;
        else if (z == 1)
          Kb[((size_t)(b * 16 + h) * 2048 + t) * 64 + d] = cb;
        else
          VTb[((size_t)(b * 16 + h) * 64 + d) * 2048 + t] = cb;
      }
}

// ---------------------------------------------------------------------------
// Kernel 3: causal flash attention v2.
// grid (64 bh, 16 qblk), block 256 = 4 waves; QBLK=128 (wave owns 32 q-rows, 2x16 strips).
// K/V staged via global_load_lds with xor-8 swizzle (linear [64][64] tiles).
// Swapped QK^T (mfma(K,Q) -> S^T): lane owns q-row lane&15 per strip.
// Wave-uniform mask fast path + defer-rescale (THR raw 44 = 8 post-scale).
__global__ __launch_bounds__(256) void attn_kernel(const unsigned short* __restrict__ Qb,
                                                   const unsigned short* __restrict__ Kb,
                                                   const unsigned short* __restrict__ VTb,
                                                   const int* __restrict__ qpm,
                                                   const int* __restrict__ kpm,
                                                   unsigned short* __restrict__ Ob) {
  int bh = blockIdx.x;
  int qi = 15 - (int)blockIdx.y;  // heavy (long) blocks dispatch first
  int b = bh >> 4, h = bh & 15;
  int q0 = qi * 128;
  int tid = threadIdx.x, w = tid >> 6, lane = tid & 63;
  int lr = lane & 15, lg = lane >> 4;
  __shared__ __align__(16) unsigned short Ks[64 * 64];     // [kv][d], xor-8 swizzled chunks
  __shared__ __align__(16) unsigned short Vs[64 * 64];     // [d][kv], xor-8 swizzled chunks
  __shared__ __align__(16) unsigned short Ps[4][32 * 72];  // per-wave P[q][kv], +8 pad

  const unsigned short* Kbh = Kb + (size_t)bh * 2048 * 64;
  const unsigned short* Vbh = VTb + (size_t)bh * 64 * 2048;
  int qb0 = q0 + w * 32;

  short8 qf[2][2];
#pragma unroll
  for (int s = 0; s < 2; ++s) {
    const unsigned short* qp = Qb + ((size_t)bh * 2048 + qb0 + s * 16 + lr) * 64 + lg * 8;
    qf[s][0] = *(const short8*)qp;
    qf[s][1] = *(const short8*)(qp + 32);
  }

  f32x4 o[2][4];
  float m[2] = {-1e30f, -1e30f}, l[2] = {0.f, 0.f};
#pragma unroll
  for (int s = 0; s < 2; ++s)
#pragma unroll
    for (int dt = 0; dt < 4; ++dt) o[s][dt] = (f32x4){0.f, 0.f, 0.f, 0.f};

  const float CS = 0.125f * 1.44269504f;  // (1/sqrt(Dh)) * log2(e)
  int ntiles = 2 * qi + 2;
  for (int it = 0; it < ntiles; ++it) {
    int kv0 = it * 64;
    __syncthreads();  // prev-iter LDS reads done before overwrite
#pragma unroll
    for (int j = 0; j < 2; ++j) {
      int base = j * 256 + w * 64;  // wave-uniform LDS base; lane-linear dest
      int u = base + lane;
      int row = u >> 3, c = u & 7, cs = c ^ (row & 7);  // inverse-swizzled source
      gl_lds16(Kbh + (size_t)(kv0 + row) * 64 + cs * 8, &Ks[base * 8]);
      gl_lds16(Vbh + (size_t)row * 2048 + kv0 + cs * 8, &Vs[base * 8]);
    }
    unsigned long long kmask = __ballot(kpm[b * 2048 + kv0 + lane] != 0);
    __syncthreads();
    bool allk = (kmask == ~0ull);

    // K fragments once per tile, reused by both strips
    short8 kf[4][2];
#pragma unroll
    for (int t = 0; t < 4; ++t) {
      int krow = t * 16 + lr;
#pragma unroll
      for (int c = 0; c < 2; ++c) {
        int slot = (c * 4 + lg) ^ (krow & 7);
        kf[t][c] = *(const short8*)(&Ks[krow * 64 + slot * 8]);
      }
    }

    bool act[2];
#pragma unroll
    for (int s = 0; s < 2; ++s) {
      int qb = qb0 + s * 16;
      act[s] = (kv0 <= qb + 15);
      if (!act[s]) continue;  // strip fully above diagonal: skip
      float sv[16];
#pragma unroll
      for (int t = 0; t < 4; ++t) {
        f32x4 sa = (f32x4){0.f, 0.f, 0.f, 0.f};
        sa = __builtin_amdgcn_mfma_f32_16x16x32_bf16(kf[t][0], qf[s][0], sa, 0, 0, 0);
        sa = __builtin_amdgcn_mfma_f32_16x16x32_bf16(kf[t][1], qf[s][1], sa, 0, 0, 0);
#pragma unroll
        for (int r = 0; r < 4; ++r) sv[t * 4 + r] = sa[r];
      }
      if (!(allk && kv0 + 63 <= qb)) {  // diagonal or padded: per-element mask
        int qrow = qb + lr;
#pragma unroll
        for (int t = 0; t < 4; ++t)
#pragma unroll
          for (int r = 0; r < 4; ++r) {
            int kvl = t * 16 + lg * 4 + r;
            bool ok = (kv0 + kvl <= qrow) && ((kmask >> kvl) & 1ull);
            sv[t * 4 + r] = ok ? sv[t * 4 + r] : -1e30f;
          }
      }
      // row max (tree) + cross-chunk reduce
      float x0 = fmaxf(fmaxf(sv[0], sv[1]), fmaxf(sv[2], sv[3]));
      float x1 = fmaxf(fmaxf(sv[4], sv[5]), fmaxf(sv[6], sv[7]));
      float x2 = fmaxf(fmaxf(sv[8], sv[9]), fmaxf(sv[10], sv[11]));
      float x3 = fmaxf(fmaxf(sv[12], sv[13]), fmaxf(sv[14], sv[15]));
      float pm = fmaxf(fmaxf(x0, x1), fmaxf(x2, x3));
      pm = fmaxf(pm, __shfl_xor(pm, 16));
      pm = fmaxf(pm, __shfl_xor(pm, 32));
      if (!__all(pm <= m[s] + 44.0f)) {  // defer-rescale unless max grew
        float mnew = fmaxf(m[s], pm);
        float fs = EXP2((m[s] - mnew) * CS);
        m[s] = mnew;
        float f4[4];
#pragma unroll
        for (int r = 0; r < 4; ++r) f4[r] = __shfl(fs, lg * 4 + r);
#pragma unroll
        for (int dt = 0; dt < 4; ++dt)
#pragma unroll
          for (int r = 0; r < 4; ++r) o[s][dt][r] *= f4[r];
        l[s] *= fs;
      }
#pragma unroll
      for (int i = 0; i < 16; ++i) sv[i] = EXP2((sv[i] - m[s]) * CS);
      float y0 = (sv[0] + sv[1]) + (sv[2] + sv[3]);
      float y1 = (sv[4] + sv[5]) + (sv[6] + sv[7]);
      float y2 = (sv[8] + sv[9]) + (sv[10] + sv[11]);
      float y3 = (sv[12] + sv[13]) + (sv[14] + sv[15]);
      float ps_ = (y0 + y1) + (y2 + y3);
      ps_ += __shfl_xor(ps_, 16);
      ps_ += __shfl_xor(ps_, 32);
      l[s] += ps_;
      // P -> LDS (v_cvt_pk packing, b64 writes)
#pragma unroll
      for (int t = 0; t < 4; ++t) {
        unsigned lo = pk2(sv[t * 4 + 0], sv[t * 4 + 1]);
        unsigned hi = pk2(sv[t * 4 + 2], sv[t * 4 + 3]);
        *(uint2*)(&Ps[w][(s * 16 + lr) * 72 + t * 16 + lg * 4]) = make_uint2(lo, hi);
      }
    }
    // PV for both strips, V fragments shared
#pragma unroll
    for (int st = 0; st < 2; ++st) {
      short8 pa0{}, pa1{};
      if (act[0]) pa0 = *(const short8*)(&Ps[w][(0 * 16 + lr) * 72 + st * 32 + lg * 8]);
      if (act[1]) pa1 = *(const short8*)(&Ps[w][(1 * 16 + lr) * 72 + st * 32 + lg * 8]);
#pragma unroll
      for (int dt = 0; dt < 4; ++dt) {
        int vrow = dt * 16 + lr;
        int slot = (st * 4 + lg) ^ (vrow & 7);
        short8 vf = *(const short8*)(&Vs[vrow * 64 + slot * 8]);
        if (act[0]) o[0][dt] = __builtin_amdgcn_mfma_f32_16x16x32_bf16(pa0, vf, o[0][dt], 0, 0, 0);
        if (act[1]) o[1][dt] = __builtin_amdgcn_mfma_f32_16x16x32_bf16(pa1, vf, o[1][dt], 0, 0, 0);
      }
    }
  }
  // epilogue: /l, *query_mask, write bf16 [8192][1024]
#pragma unroll
  for (int s = 0; s < 2; ++s) {
    float l4[4], qm4[4];
#pragma unroll
    for (int r = 0; r < 4; ++r) {
      l4[r] = __shfl(l[s], lg * 4 + r);
      int qg = q0 + w * 32 + s * 16 + lg * 4 + r;
      qm4[r] = (qpm[b * 2048 + qg] != 0) ? 1.f : 0.f;
    }
#pragma unroll
    for (int dt = 0; dt < 4; ++dt)
#pragma unroll
      for (int r = 0; r < 4; ++r) {
        int qg = q0 + w * 32 + s * 16 + lg * 4 + r;
        float val = o[s][dt][r] * qm4[r] / l4[r];
        Ob[(size_t)(b * 2048 + qg) * 1024 + h * 64 + dt * 16 + lr] = f2bf(val);
      }
  }
}

// ---------------------------------------------------------------------------
// Kernel 4: output projection. C(fp32) = Ob(bf16)[8192,1024] @ Wo (via WoT bf16).
__global__ __launch_bounds__(256) void out_gemm(const unsigned short* __restrict__ Ab,
                                                const unsigned short* __restrict__ WoT,
                                                float* __restrict__ C) {
  int m0 = blockIdx.x * 128, n0 = blockIdx.y * 128;
  __shared__ __align__(16) unsigned short As[128 * 32];
  __shared__ __align__(16) unsigned short Bs[128 * 32];
  int tid = threadIdx.x, w = tid >> 6, lane = tid & 63;
  int lr = lane & 15, lg = lane >> 4;
  int wm = w >> 1, wn = w & 1;
  f32x4 acc[4][4];
#pragma unroll
  for (int i = 0; i < 4; ++i)
#pragma unroll
    for (int j = 0; j < 4; ++j) acc[i][j] = (f32x4){0.f, 0.f, 0.f, 0.f};

  for (int k0 = 0; k0 < 1024; k0 += 32) {
#pragma unroll
    for (int c = 0; c < 2; ++c) {
      int base = c * 256 + w * 64;
      int u = base + lane;
      int row = u >> 2, sl = u & 3;
      int ssl = sl ^ (row & 3);
      gl_lds16(Ab + (size_t)(m0 + row) * 1024 + k0 + ssl * 8, &As[base * 8]);
      gl_lds16(WoT + (size_t)(n0 + row) * 1024 + k0 + ssl * 8, &Bs[base * 8]);
    }
    __syncthreads();
    short8 af[4], bfr[4];
#pragma unroll
    for (int mi = 0; mi < 4; ++mi) {
      int row = wm * 64 + mi * 16 + lr;
      af[mi] = *(const short8*)(&As[(row * 4 + (lg ^ (row & 3))) * 8]);
    }
#pragma unroll
    for (int ni = 0; ni < 4; ++ni) {
      int row = wn * 64 + ni * 16 + lr;
      bfr[ni] = *(const short8*)(&Bs[(row * 4 + (lg ^ (row & 3))) * 8]);
    }
#pragma unroll
    for (int mi = 0; mi < 4; ++mi)
#pragma unroll
      for (int ni = 0; ni < 4; ++ni)
        acc[mi][ni] = __builtin_amdgcn_mfma_f32_16x16x32_bf16(af[mi], bfr[ni], acc[mi][ni], 0, 0, 0);
    __syncthreads();
  }
#pragma unroll
  for (int mi = 0; mi < 4; ++mi)
#pragma unroll
    for (int ni = 0; ni < 4; ++ni)
#pragma unroll
      for (int r = 0; r < 4; ++r) {
        int m = m0 + wm * 64 + mi * 16 + lg * 4 + r;
        int n = n0 + wn * 64 + ni * 16 + lr;
        C[(size_t)m * 1024 + n] = acc[mi][ni][r];
      }
}

// ---------------------------------------------------------------------------
extern "C" void kernel_launch(void* const* d_in, const int* in_sizes, int n_in,
                              void* d_out, int out_size, void* d_ws, size_t ws_size,
                              hipStream_t stream) {
  const float* q = (const float*)d_in[0];
  const float* k = (const float*)d_in[1];
  const float* v = (const float*)d_in[2];
  const int* qpm = (const int*)d_in[3];
  const int* kpm = (const int*)d_in[4];
  const float* Wq = (const float*)d_in[5];
  const float* Wk = (const float*)d_in[6];
  const float* Wv = (const float*)d_in[7];
  const float* Wo = (const float*)d_in[8];
  float* out = (float*)d_out;

  char* ws = (char*)d_ws;  // needs 104 MB
  unsigned short* WT  = (unsigned short*)(ws);                       // 8 MB
  unsigned short* Xb  = (unsigned short*)(ws + ((size_t)8 << 20));   // 48 MB (dead after proj)
  unsigned short* Ob  = (unsigned short*)(ws + ((size_t)8 << 20));   // 16 MB (aliases Xb)
  unsigned short* Qb  = (unsigned short*)(ws + ((size_t)56 << 20));  // 16 MB
  unsigned short* Kb  = (unsigned short*)(ws + ((size_t)72 << 20));  // 16 MB
  unsigned short* VTb = (unsigned short*)(ws + ((size_t)88 << 20));  // 16 MB

  prep_w<<<dim3(16, 16, 4), 256, 0, stream>>>(Wq, Wk, Wv, Wo, WT);
  prep_x<<<dim3(4096, 1, 3), 256, 0, stream>>>(q, k, v, Xb);
  proj_gemm<<<dim3(64, 8, 3), 256, 0, stream>>>(Xb, WT, Qb, Kb, VTb);
  attn_kernel<<<dim3(64, 16), 256, 0, stream>>>(Qb, Kb, VTb, qpm, kpm, Ob);
  out_gemm<<<dim3(64, 8), 256, 0, stream>>>(Ob, WT + (size_t)3 * 1024 * 1024, out);
}